// Round 1
// baseline (10416.547 us; speedup 1.0000x reference)
//
#include <hip/hip_runtime.h>

// ---------------- problem dims ----------------
#define S_LEN 128
#define BATCH 64
#define EDIM  512
#define PLEN  160
#define PDIM  512
#define HDIM  1024
#define G3    3072      // 3*H
#define NBLK  256
#define NTHR  256

typedef _Float16 half8v  __attribute__((ext_vector_type(8)));
typedef _Float16 half4v  __attribute__((ext_vector_type(4)));
typedef float    f32x4   __attribute__((ext_vector_type(4)));

// ---------------- workspace layout (bytes) ----------------
#define OFF_CTRL  ((size_t)0)                               // 4096 B: [0]=barrier ctr, [64..127]=quad flags
#define OFF_WIH   ((size_t)4096)                            // fp16 [3072][1024]
#define OFF_WHH   (OFF_WIH  + (size_t)G3*HDIM*2)            // fp16 [3072][1024]
#define OFF_WQ    (OFF_WHH  + (size_t)G3*HDIM*2)            // fp16 [512][1024]
#define OFF_INC   (OFF_WQ   + (size_t)PDIM*HDIM*2)          // fp16 [128][64][512]
#define OFF_HH    (OFF_INC  + (size_t)S_LEN*BATCH*EDIM*2)   // fp16 [64][1024]
#define OFF_QH    (OFF_HH   + (size_t)BATCH*HDIM*2)         // fp16 [64][512]
#define OFF_CTXH  (OFF_QH   + (size_t)BATCH*PDIM*2)         // fp16 [64][512]
#define OFF_GACC  (OFF_CTXH + (size_t)BATCH*PDIM*2)         // f32  [64][3072]
#define OFF_GHN   (OFF_GACC + (size_t)BATCH*G3*4)           // f32  [64][1024]
#define OFF_PM    (OFF_GHN  + (size_t)BATCH*HDIM*4)         // f32  [64][4]
#define OFF_PS    (OFF_PM   + (size_t)BATCH*4*4)            // f32  [64][4]
#define OFF_PC    (OFF_PS   + (size_t)BATCH*4*4)            // f32  [64][4][512]
// total ~23.9 MB

__global__ void init_ctrl(unsigned* u) {
    int i = threadIdx.x + blockIdx.x * blockDim.x;
    if (i < 1024) u[i] = 0u;
}

__device__ __forceinline__ float wave_sum(float v) {
    v += __shfl_xor(v, 32); v += __shfl_xor(v, 16); v += __shfl_xor(v, 8);
    v += __shfl_xor(v, 4);  v += __shfl_xor(v, 2);  v += __shfl_xor(v, 1);
    return v;
}
__device__ __forceinline__ float wave_max(float v) {
    v = fmaxf(v, __shfl_xor(v, 32)); v = fmaxf(v, __shfl_xor(v, 16));
    v = fmaxf(v, __shfl_xor(v, 8));  v = fmaxf(v, __shfl_xor(v, 4));
    v = fmaxf(v, __shfl_xor(v, 2));  v = fmaxf(v, __shfl_xor(v, 1));
    return v;
}

// grid barrier: monotonic counter, agent scope.  After __syncthreads all of the
// block's global stores are in L2 (barrier drains vmcnt); thread0's acq_rel RMW
// does the L2 writeback / invalidate for the whole CU+XCD path.
__device__ __forceinline__ void gbar(unsigned* ctr, unsigned& gen) {
    gen++;
    __syncthreads();
    if (threadIdx.x == 0) {
        __hip_atomic_fetch_add(ctr, 1u, __ATOMIC_ACQ_REL, __HIP_MEMORY_SCOPE_AGENT);
        const unsigned tgt = gen * (unsigned)NBLK;
        while (__hip_atomic_load(ctr, __ATOMIC_RELAXED, __HIP_MEMORY_SCOPE_AGENT) < tgt)
            __builtin_amdgcn_s_sleep(2);
        __hip_atomic_load(ctr, __ATOMIC_ACQUIRE, __HIP_MEMORY_SCOPE_AGENT);
    }
    __syncthreads();
}

// one 16x16 output tile accumulation: D[m,n] += sum_k A[m,k] * W[n,k]
// A: [16 rows x K] row-major (pre-offset to the wave's 16-row stripe), lda
// Bb: weight rows base (pre-offset to col-tile's first row), ldb; reads 8
// consecutive k per lane -> matches verified gfx950 B^T-layout GEMM pattern.
__device__ __forceinline__ void mfma_acc(f32x4& acc, const _Float16* __restrict__ A, int lda,
                                         const _Float16* __restrict__ Bb, int ldb,
                                         int ksteps, int lane) {
    const _Float16* ap = A  + (size_t)(lane & 15) * lda + ((lane >> 4) << 3);
    const _Float16* bp = Bb + (size_t)(lane & 15) * ldb + ((lane >> 4) << 3);
    for (int ks = 0; ks < ksteps; ++ks) {
        half8v av = *(const half8v*)ap;
        half8v bv = *(const half8v*)bp;
        acc = __builtin_amdgcn_mfma_f32_16x16x32_f16(av, bv, acc, 0, 0, 0);
        ap += 32; bp += 32;
    }
}

__global__ __launch_bounds__(NTHR, 1) void gru_main(
    const float* __restrict__ incoming, const float* __restrict__ post,
    const float* __restrict__ h_init,   const float* __restrict__ w_ih,
    const float* __restrict__ w_hh,     const float* __restrict__ b_ih,
    const float* __restrict__ b_hh,     const float* __restrict__ wq,
    const float* __restrict__ bq,       const int* __restrict__ length,
    const int* __restrict__ post_length, float* __restrict__ out,
    char* __restrict__ ws)
{
    const int tid  = threadIdx.x;
    const int blk  = blockIdx.x;
    const int lane = tid & 63;
    const int wv   = tid >> 6;

    unsigned* ctr    = (unsigned*)(ws + OFF_CTRL);
    unsigned* qflags = (unsigned*)(ws + OFF_CTRL) + 64;
    _Float16* wih_h  = (_Float16*)(ws + OFF_WIH);
    _Float16* whh_h  = (_Float16*)(ws + OFF_WHH);
    _Float16* wq_h   = (_Float16*)(ws + OFF_WQ);
    _Float16* inc_h  = (_Float16*)(ws + OFF_INC);
    _Float16* h_h    = (_Float16*)(ws + OFF_HH);
    _Float16* query_h= (_Float16*)(ws + OFF_QH);
    _Float16* ctx_h  = (_Float16*)(ws + OFF_CTXH);
    float*    gacc   = (float*)(ws + OFF_GACC);
    float*    ghn    = (float*)(ws + OFF_GHN);
    float*    pm     = (float*)(ws + OFF_PM);
    float*    pS     = (float*)(ws + OFF_PS);
    float*    pc     = (float*)(ws + OFF_PC);

    __shared__ _Float16 s_post[40 * PDIM];   // 40 KB: this block's p-quarter of post, fp16
    __shared__ float s_scores[48];
    __shared__ float s_w[48];
    __shared__ float s_bc[2];

    unsigned gen = 0;

    // ---------------- init: fp32 -> fp16 conversions (flat, grid-wide) ----------------
    {
        const int NV4_WIH = G3*HDIM/4, NV4_WHH = G3*HDIM/4, NV4_WQ = PDIM*HDIM/4;
        const int NV4_INC = S_LEN*BATCH*EDIM/4;
        const int TOT = NV4_WIH + NV4_WHH + NV4_WQ + NV4_INC;
        for (int i = blk*NTHR + tid; i < TOT; i += NBLK*NTHR) {
            const float* s; _Float16* dp; int o;
            if (i < NV4_WIH)                         { s = w_ih;     dp = wih_h; o = i; }
            else if (i < NV4_WIH + NV4_WHH)          { s = w_hh;     dp = whh_h; o = i - NV4_WIH; }
            else if (i < NV4_WIH + NV4_WHH + NV4_WQ) { s = wq;       dp = wq_h;  o = i - NV4_WIH - NV4_WHH; }
            else                                     { s = incoming; dp = inc_h; o = i - NV4_WIH - NV4_WHH - NV4_WQ; }
            f32x4 v = *(const f32x4*)(s + (size_t)o*4);
            half4v hv4 = {(_Float16)v.x, (_Float16)v.y, (_Float16)v.z, (_Float16)v.w};
            *(half4v*)(dp + (size_t)o*4) = hv4;
        }
        for (int i = blk*NTHR + tid; i < BATCH*HDIM; i += NBLK*NTHR)
            h_h[i] = (_Float16)h_init[i & (HDIM-1)];
    }
    // this block's attention slice: batch ab, p-quarter aq
    const int ab = blk >> 2;
    const int aq = blk & 3;
    const int p0 = aq * 40;
    for (int i = tid; i < 40*PDIM; i += NTHR) {
        int p = i >> 9, d = i & (PDIM-1);
        s_post[i] = (_Float16)post[((size_t)(p0+p)*BATCH + ab)*PDIM + d];
    }
    gbar(ctr, gen);   // gen 1: weights/inc/h ready

    // ---------------- time loop ----------------
    for (int t = 0; t < S_LEN; ++t) {
        // ======== stage A: h/x-dependent matmuls ========
        if (blk < 128) {
            // r,z gates: gacc[c] = xt@Wih[:, :512]^T + h@Whh^T + b_ih + b_hh, c in [0,2048)
            const int c0 = blk * 16;
            f32x4 acc = {0.f,0.f,0.f,0.f};
            mfma_acc(acc, inc_h + ((size_t)t*BATCH + wv*16)*EDIM, EDIM,
                     wih_h + (size_t)c0*HDIM, HDIM, EDIM/32, lane);
            mfma_acc(acc, h_h + (size_t)(wv*16)*HDIM, HDIM,
                     whh_h + (size_t)c0*HDIM, HDIM, HDIM/32, lane);
            const int c  = c0 + (lane & 15);
            const float bs = b_ih[c] + b_hh[c];
            const int r0 = wv*16 + ((lane >> 4) << 2);
            #pragma unroll
            for (int r = 0; r < 4; ++r)
                gacc[(size_t)(r0+r)*G3 + c] = acc[r] + bs;
        } else if (blk < 192) {
            // n gate, x-part and h-part SEPARATE (n = tanh(i_n + r*h_n))
            const int c0 = 2048 + (blk - 128) * 16;
            const int c  = c0 + (lane & 15);
            const int r0 = wv*16 + ((lane >> 4) << 2);
            f32x4 acc = {0.f,0.f,0.f,0.f};
            mfma_acc(acc, h_h + (size_t)(wv*16)*HDIM, HDIM,
                     whh_h + (size_t)c0*HDIM, HDIM, HDIM/32, lane);
            const float bh = b_hh[c];
            #pragma unroll
            for (int r = 0; r < 4; ++r)
                ghn[(size_t)(r0+r)*HDIM + (c - 2048)] = acc[r] + bh;
            f32x4 acc2 = {0.f,0.f,0.f,0.f};
            mfma_acc(acc2, inc_h + ((size_t)t*BATCH + wv*16)*EDIM, EDIM,
                     wih_h + (size_t)c0*HDIM, HDIM, EDIM/32, lane);
            const float bi = b_ih[c];
            #pragma unroll
            for (int r = 0; r < 4; ++r)
                gacc[(size_t)(r0+r)*G3 + c] = acc2[r] + bi;
        } else if (blk < 224) {
            // query = h @ wq^T + bq  -> fp16
            const int q0 = (blk - 192) * 16;
            f32x4 acc = {0.f,0.f,0.f,0.f};
            mfma_acc(acc, h_h + (size_t)(wv*16)*HDIM, HDIM,
                     wq_h + (size_t)q0*HDIM, HDIM, HDIM/32, lane);
            const int c  = q0 + (lane & 15);
            const float bb = bq[c];
            const int r0 = wv*16 + ((lane >> 4) << 2);
            #pragma unroll
            for (int r = 0; r < 4; ++r)
                query_h[(size_t)(r0+r)*PDIM + c] = (_Float16)(acc[r] + bb);
        }
        gbar(ctr, gen);

        // ======== stage B: attention (all 256 blocks; 4 per batch over p-quarters) ========
        {
            const int plen = post_length[ab];
            half8v qv = *(const half8v*)(query_h + (size_t)ab*PDIM + lane*8);
            for (int p = wv; p < 40; p += 4) {
                half8v pv = *(const half8v*)(&s_post[p*PDIM + lane*8]);
                float sdot = 0.f;
                #pragma unroll
                for (int j = 0; j < 8; ++j) sdot += (float)pv[j] * (float)qv[j];
                sdot = wave_sum(sdot);
                if (lane == 0) s_scores[p] = (p0 + p < plen) ? sdot : -1e30f;
            }
            __syncthreads();
            if (wv == 0) {
                float m = (lane < 40) ? s_scores[lane] : -1e30f;
                m = wave_max(m);
                if (lane == 0) s_bc[0] = m;
            }
            __syncthreads();
            const float mx = s_bc[0];
            if (tid < 40) {
                float w = (p0 + tid < plen) ? __expf(s_scores[tid] - mx) : 0.f;
                s_w[tid] = w;
            }
            __syncthreads();
            if (wv == 0) {
                float sw = (lane < 40) ? s_w[lane] : 0.f;
                sw = wave_sum(sw);
                if (lane == 0) { pm[ab*4 + aq] = mx; pS[ab*4 + aq] = sw; }
            }
            // partial context: each thread owns 2 d's
            const int d0 = tid * 2;
            float ca = 0.f, cb = 0.f;
            for (int p = 0; p < 40; ++p) {
                float wp = s_w[p];
                ca += wp * (float)s_post[p*PDIM + d0];
                cb += wp * (float)s_post[p*PDIM + d0 + 1];
            }
            pc[((size_t)ab*4 + aq)*PDIM + d0]     = ca;
            pc[((size_t)ab*4 + aq)*PDIM + d0 + 1] = cb;
            // quad sync (monotonic: 4 increments per step)
            __syncthreads();
            if (tid == 0) {
                __hip_atomic_fetch_add(&qflags[ab], 1u, __ATOMIC_ACQ_REL, __HIP_MEMORY_SCOPE_AGENT);
                const unsigned tgt = 4u * (unsigned)(t + 1);
                while (__hip_atomic_load(&qflags[ab], __ATOMIC_RELAXED, __HIP_MEMORY_SCOPE_AGENT) < tgt)
                    __builtin_amdgcn_s_sleep(1);
                __hip_atomic_load(&qflags[ab], __ATOMIC_ACQUIRE, __HIP_MEMORY_SCOPE_AGENT);
            }
            __syncthreads();
            // combine the 4 partials for our 128-d range -> fp16 ctx
            if (tid < 128) {
                const int d = aq*128 + tid;
                float m0 = pm[ab*4+0], m1 = pm[ab*4+1], m2 = pm[ab*4+2], m3 = pm[ab*4+3];
                float mm = fmaxf(fmaxf(m0, m1), fmaxf(m2, m3));
                float a0 = __expf(m0-mm), a1 = __expf(m1-mm), a2 = __expf(m2-mm), a3 = __expf(m3-mm);
                float den = a0*pS[ab*4+0] + a1*pS[ab*4+1] + a2*pS[ab*4+2] + a3*pS[ab*4+3];
                float val = a0*pc[((size_t)ab*4+0)*PDIM + d] + a1*pc[((size_t)ab*4+1)*PDIM + d]
                          + a2*pc[((size_t)ab*4+2)*PDIM + d] + a3*pc[((size_t)ab*4+3)*PDIM + d];
                ctx_h[(size_t)ab*PDIM + d] = (_Float16)(val / den);
            }
        }
        gbar(ctr, gen);

        // ======== stage C: ctx matmul + gates + h_new (64 blocks x 16 h-cols) ========
        if (blk < 64) {
            const int j0 = blk * 16;
            f32x4 aR = {0.f,0.f,0.f,0.f}, aZ = {0.f,0.f,0.f,0.f}, aN = {0.f,0.f,0.f,0.f};
            const _Float16* ctxA = ctx_h + (size_t)(wv*16)*PDIM;
            mfma_acc(aR, ctxA, PDIM, wih_h + (size_t)(       j0)*HDIM + 512, HDIM, PDIM/32, lane);
            mfma_acc(aZ, ctxA, PDIM, wih_h + (size_t)(1024 + j0)*HDIM + 512, HDIM, PDIM/32, lane);
            mfma_acc(aN, ctxA, PDIM, wih_h + (size_t)(2048 + j0)*HDIM + 512, HDIM, PDIM/32, lane);
            const int j  = j0 + (lane & 15);
            const int r0 = wv*16 + ((lane >> 4) << 2);
            #pragma unroll
            for (int r = 0; r < 4; ++r) {
                const int b = r0 + r;
                float gr = gacc[(size_t)b*G3 +        j] + aR[r];
                float gz = gacc[(size_t)b*G3 + 1024 + j] + aZ[r];
                float gn = gacc[(size_t)b*G3 + 2048 + j] + aN[r];
                float gh = ghn[(size_t)b*HDIM + j];
                float rg = 1.f / (1.f + __expf(-gr));
                float zg = 1.f / (1.f + __expf(-gz));
                float e2 = __expf(2.f * (gn + rg * gh));
                float ng = 1.f - 2.f / (e2 + 1.f);            // tanh
                float hp = (t == 0) ? h_init[j]
                                    : out[(size_t)(t-1)*BATCH*HDIM + (size_t)b*HDIM + j];
                float hv = (1.f - zg) * ng + zg * hp;
                if (length[b] <= t) hv = 0.f;
                out[(size_t)t*BATCH*HDIM + (size_t)b*HDIM + j] = hv;
                h_h[(size_t)b*HDIM + j] = (_Float16)hv;
                if (t == S_LEN - 1)
                    out[(size_t)S_LEN*BATCH*HDIM + (size_t)b*HDIM + j] = hv;   // h_last
            }
        }
        gbar(ctr, gen);
    }
}

extern "C" void kernel_launch(void* const* d_in, const int* in_sizes, int n_in,
                              void* d_out, int out_size, void* d_ws, size_t ws_size,
                              hipStream_t stream) {
    (void)in_sizes; (void)n_in; (void)out_size; (void)ws_size;
    const float* incoming    = (const float*)d_in[0];
    const float* post        = (const float*)d_in[1];
    const float* h_init      = (const float*)d_in[2];
    const float* w_ih        = (const float*)d_in[3];
    const float* w_hh        = (const float*)d_in[4];
    const float* b_ih        = (const float*)d_in[5];
    const float* b_hh        = (const float*)d_in[6];
    const float* wq          = (const float*)d_in[7];
    const float* bq          = (const float*)d_in[8];
    const int*   length      = (const int*)d_in[9];
    const int*   post_length = (const int*)d_in[10];
    float* out = (float*)d_out;

    init_ctrl<<<4, 256, 0, stream>>>((unsigned*)d_ws);
    gru_main<<<NBLK, NTHR, 0, stream>>>(incoming, post, h_init, w_ih, w_hh, b_ih, b_hh,
                                        wq, bq, length, post_length, out, (char*)d_ws);
}

// Round 2
// 7125.379 us; speedup vs baseline: 1.4619x; 1.4619x over previous
//
#include <hip/hip_runtime.h>

// ---------------- problem dims ----------------
#define S_LEN 128
#define BATCH 64
#define EDIM  512
#define PLEN  160
#define PDIM  512
#define HDIM  1024
#define G3    3072      // 3*H
#define NBLK  256
#define NTHR  256

typedef _Float16 half8v  __attribute__((ext_vector_type(8)));
typedef _Float16 half4v  __attribute__((ext_vector_type(4)));
typedef _Float16 half2v  __attribute__((ext_vector_type(2)));
typedef float    f32x4   __attribute__((ext_vector_type(4)));

// ---------------- workspace layout (bytes) ----------------
// ctrl region (uints): [0..4096) gensig (16 lines @ stride 256 uints)
//                      [4096..12288) arrive (256 slots @ stride 32 uints)
//                      [12288..20480) qarr (64 quads x 4 members @ stride 32 uints)
#define CTRL_UINTS 24576
#define OFF_CTRL  ((size_t)0)                               // 96 KiB
#define OFF_WIH   ((size_t)(CTRL_UINTS*4))                  // fp16 [3072][1024]
#define OFF_WHH   (OFF_WIH  + (size_t)G3*HDIM*2)            // fp16 [3072][1024]
#define OFF_WQ    (OFF_WHH  + (size_t)G3*HDIM*2)            // fp16 [512][1024]
#define OFF_INC   (OFF_WQ   + (size_t)PDIM*HDIM*2)          // fp16 [128][64][512]
#define OFF_HH    (OFF_INC  + (size_t)S_LEN*BATCH*EDIM*2)   // fp16 [64][1024]
#define OFF_QH    (OFF_HH   + (size_t)BATCH*HDIM*2)         // fp16 [64][512]
#define OFF_CTXH  (OFF_QH   + (size_t)BATCH*PDIM*2)         // fp16 [64][512]
#define OFF_GACC  (OFF_CTXH + (size_t)BATCH*PDIM*2)         // f32  [64][3072]
#define OFF_GHN   (OFF_GACC + (size_t)BATCH*G3*4)           // f32  [64][1024]
#define OFF_PM    (OFF_GHN  + (size_t)BATCH*HDIM*4)         // f32  [64][4]
#define OFF_PS    (OFF_PM   + (size_t)BATCH*4*4)            // f32  [64][4]
#define OFF_PC    (OFF_PS   + (size_t)BATCH*4*4)            // f32  [64][4][512]
// total ~24 MB

__global__ void init_ctrl(unsigned* u) {
    int i = threadIdx.x + blockIdx.x * blockDim.x;
    if (i < CTRL_UINTS) u[i] = 0u;
}

__device__ __forceinline__ float wave_sum(float v) {
    v += __shfl_xor(v, 32); v += __shfl_xor(v, 16); v += __shfl_xor(v, 8);
    v += __shfl_xor(v, 4);  v += __shfl_xor(v, 2);  v += __shfl_xor(v, 1);
    return v;
}
__device__ __forceinline__ float wave_max(float v) {
    v = fmaxf(v, __shfl_xor(v, 32)); v = fmaxf(v, __shfl_xor(v, 16));
    v = fmaxf(v, __shfl_xor(v, 8));  v = fmaxf(v, __shfl_xor(v, 4));
    v = fmaxf(v, __shfl_xor(v, 2));  v = fmaxf(v, __shfl_xor(v, 1));
    return v;
}

// Contention-free grid barrier: per-block padded arrive flags (pure release
// stores, no RMW), block 0 aggregates with 256 parallel pollers, broadcast via
// 16 replicated generation lines (~16 pollers per line).
__device__ __forceinline__ void gbar(unsigned* ctrlU, unsigned& gen, int tid, int blk) {
    gen++;
    __syncthreads();
    unsigned* gensig = ctrlU;            // 16 lines, stride 256 uints
    unsigned* arrive = ctrlU + 4096;     // 256 slots, stride 32 uints
    if (blk == 0) {
        if (tid > 0) {
            unsigned* fl = &arrive[tid * 32];
            while (__hip_atomic_load(fl, __ATOMIC_RELAXED, __HIP_MEMORY_SCOPE_AGENT) < gen)
                __builtin_amdgcn_s_sleep(1);
            __hip_atomic_load(fl, __ATOMIC_ACQUIRE, __HIP_MEMORY_SCOPE_AGENT);
        }
        __syncthreads();
        if (tid < 16)
            __hip_atomic_store(&gensig[tid * 256], gen, __ATOMIC_RELEASE, __HIP_MEMORY_SCOPE_AGENT);
        __syncthreads();
    } else {
        if (tid == 0) {
            __hip_atomic_store(&arrive[blk * 32], gen, __ATOMIC_RELEASE, __HIP_MEMORY_SCOPE_AGENT);
            unsigned* sig = &gensig[(blk & 15) * 256];
            while (__hip_atomic_load(sig, __ATOMIC_RELAXED, __HIP_MEMORY_SCOPE_AGENT) < gen)
                __builtin_amdgcn_s_sleep(1);
            __hip_atomic_load(sig, __ATOMIC_ACQUIRE, __HIP_MEMORY_SCOPE_AGENT);
        }
        __syncthreads();
    }
}

// one 16x16 output tile accumulation: D[m,n] += sum_k A[m,k] * W[n,k]
__device__ __forceinline__ void mfma_acc(f32x4& acc, const _Float16* __restrict__ A, int lda,
                                         const _Float16* __restrict__ Bb, int ldb,
                                         int ksteps, int lane) {
    const _Float16* ap = A  + (size_t)(lane & 15) * lda + ((lane >> 4) << 3);
    const _Float16* bp = Bb + (size_t)(lane & 15) * ldb + ((lane >> 4) << 3);
    #pragma unroll
    for (int ks = 0; ks < ksteps; ++ks) {
        half8v av = *(const half8v*)ap;
        half8v bv = *(const half8v*)bp;
        acc = __builtin_amdgcn_mfma_f32_16x16x32_f16(av, bv, acc, 0, 0, 0);
        ap += 32; bp += 32;
    }
}

__global__ __launch_bounds__(NTHR, 1) void gru_main(
    const float* __restrict__ incoming, const float* __restrict__ post,
    const float* __restrict__ h_init,   const float* __restrict__ w_ih,
    const float* __restrict__ w_hh,     const float* __restrict__ b_ih,
    const float* __restrict__ b_hh,     const float* __restrict__ wq,
    const float* __restrict__ bq,       const int* __restrict__ length,
    const int* __restrict__ post_length, float* __restrict__ out,
    char* __restrict__ ws)
{
    const int tid  = threadIdx.x;
    const int blk  = blockIdx.x;
    const int lane = tid & 63;
    const int wv   = tid >> 6;

    unsigned* ctrlU  = (unsigned*)(ws + OFF_CTRL);
    unsigned* qarr   = ctrlU + 12288;              // 64 quads x 4 @ stride 32
    _Float16* wih_h  = (_Float16*)(ws + OFF_WIH);
    _Float16* whh_h  = (_Float16*)(ws + OFF_WHH);
    _Float16* wq_h   = (_Float16*)(ws + OFF_WQ);
    _Float16* inc_h  = (_Float16*)(ws + OFF_INC);
    _Float16* h_h    = (_Float16*)(ws + OFF_HH);
    _Float16* query_h= (_Float16*)(ws + OFF_QH);
    _Float16* ctx_h  = (_Float16*)(ws + OFF_CTXH);
    float*    gacc   = (float*)(ws + OFF_GACC);
    float*    ghn    = (float*)(ws + OFF_GHN);
    float*    pm     = (float*)(ws + OFF_PM);
    float*    pS     = (float*)(ws + OFF_PS);
    float*    pc     = (float*)(ws + OFF_PC);

    __shared__ _Float16 s_post[40 * PDIM];   // 40 KB: this block's p-quarter of post, fp16
    __shared__ float s_scores[48];
    __shared__ float s_w[48];
    __shared__ float s_bc[2];

    unsigned gen = 0;

    // ---------------- init: fp32 -> fp16 conversions (flat, grid-wide) ----------------
    {
        const int NV4_WIH = G3*HDIM/4, NV4_WHH = G3*HDIM/4, NV4_WQ = PDIM*HDIM/4;
        const int NV4_INC = S_LEN*BATCH*EDIM/4;
        const int TOT = NV4_WIH + NV4_WHH + NV4_WQ + NV4_INC;
        for (int i = blk*NTHR + tid; i < TOT; i += NBLK*NTHR) {
            const float* s; _Float16* dp; int o;
            if (i < NV4_WIH)                         { s = w_ih;     dp = wih_h; o = i; }
            else if (i < NV4_WIH + NV4_WHH)          { s = w_hh;     dp = whh_h; o = i - NV4_WIH; }
            else if (i < NV4_WIH + NV4_WHH + NV4_WQ) { s = wq;       dp = wq_h;  o = i - NV4_WIH - NV4_WHH; }
            else                                     { s = incoming; dp = inc_h; o = i - NV4_WIH - NV4_WHH - NV4_WQ; }
            f32x4 v = *(const f32x4*)(s + (size_t)o*4);
            half4v hv4 = {(_Float16)v.x, (_Float16)v.y, (_Float16)v.z, (_Float16)v.w};
            *(half4v*)(dp + (size_t)o*4) = hv4;
        }
        for (int i = blk*NTHR + tid; i < BATCH*HDIM; i += NBLK*NTHR)
            h_h[i] = (_Float16)h_init[i & (HDIM-1)];
    }
    // this block's attention slice: batch ab, p-quarter aq
    const int ab = blk >> 2;
    const int aq = blk & 3;
    const int p0 = aq * 40;
    for (int i = tid; i < 40*PDIM; i += NTHR) {
        int p = i >> 9, d = i & (PDIM-1);
        s_post[i] = (_Float16)post[((size_t)(p0+p)*BATCH + ab)*PDIM + d];
    }
    const int plen = post_length[ab];

    // ---------------- per-block loop-invariant hoists ----------------
    float bs = 0.f, bh = 0.f, bi = 0.f, bb = 0.f;
    if (blk < 128)      { int c = blk*16 + (lane & 15); bs = b_ih[c] + b_hh[c]; }
    else if (blk < 192) { int c = 2048 + (blk-128)*16 + (lane & 15); bh = b_hh[c]; bi = b_ih[c]; }
    else if (blk < 224) { int c = (blk-192)*16 + (lane & 15); bb = bq[c]; }
    float hp[4]; int lenb[4];
    if (blk < 64) {
        const int j  = blk*16 + (lane & 15);
        const int r0 = wv*16 + ((lane >> 4) << 2);
        const float hi = h_init[j];
        #pragma unroll
        for (int r = 0; r < 4; ++r) { hp[r] = hi; lenb[r] = length[r0 + r]; }
    }

    gbar(ctrlU, gen, tid, blk);   // weights/inc/h ready

    // ---------------- time loop ----------------
    for (int t = 0; t < S_LEN; ++t) {
        // ======== stage A: h/x-dependent matmuls ========
        if (blk < 128) {
            // r,z gates: gacc[c] = xt@Wih[:, :512]^T + h@Whh^T + biases, c in [0,2048)
            const int c0 = blk * 16;
            f32x4 acc = {0.f,0.f,0.f,0.f};
            mfma_acc(acc, inc_h + ((size_t)t*BATCH + wv*16)*EDIM, EDIM,
                     wih_h + (size_t)c0*HDIM, HDIM, EDIM/32, lane);
            mfma_acc(acc, h_h + (size_t)(wv*16)*HDIM, HDIM,
                     whh_h + (size_t)c0*HDIM, HDIM, HDIM/32, lane);
            const int c  = c0 + (lane & 15);
            const int r0 = wv*16 + ((lane >> 4) << 2);
            #pragma unroll
            for (int r = 0; r < 4; ++r)
                gacc[(size_t)(r0+r)*G3 + c] = acc[r] + bs;
        } else if (blk < 192) {
            // n gate, x-part and h-part SEPARATE (n = tanh(i_n + r*h_n))
            const int c0 = 2048 + (blk - 128) * 16;
            const int c  = c0 + (lane & 15);
            const int r0 = wv*16 + ((lane >> 4) << 2);
            f32x4 acc = {0.f,0.f,0.f,0.f};
            mfma_acc(acc, h_h + (size_t)(wv*16)*HDIM, HDIM,
                     whh_h + (size_t)c0*HDIM, HDIM, HDIM/32, lane);
            #pragma unroll
            for (int r = 0; r < 4; ++r)
                ghn[(size_t)(r0+r)*HDIM + (c - 2048)] = acc[r] + bh;
            f32x4 acc2 = {0.f,0.f,0.f,0.f};
            mfma_acc(acc2, inc_h + ((size_t)t*BATCH + wv*16)*EDIM, EDIM,
                     wih_h + (size_t)c0*HDIM, HDIM, EDIM/32, lane);
            #pragma unroll
            for (int r = 0; r < 4; ++r)
                gacc[(size_t)(r0+r)*G3 + c] = acc2[r] + bi;
        } else if (blk < 224) {
            // query = h @ wq^T + bq  -> fp16
            const int q0 = (blk - 192) * 16;
            f32x4 acc = {0.f,0.f,0.f,0.f};
            mfma_acc(acc, h_h + (size_t)(wv*16)*HDIM, HDIM,
                     wq_h + (size_t)q0*HDIM, HDIM, HDIM/32, lane);
            const int c  = q0 + (lane & 15);
            const int r0 = wv*16 + ((lane >> 4) << 2);
            #pragma unroll
            for (int r = 0; r < 4; ++r)
                query_h[(size_t)(r0+r)*PDIM + c] = (_Float16)(acc[r] + bb);
        }
        gbar(ctrlU, gen, tid, blk);

        // ======== stage B: attention (4 blocks per batch over p-quarters) ========
        {
            half8v qv = *(const half8v*)(query_h + (size_t)ab*PDIM + lane*8);
            for (int p = wv; p < 40; p += 4) {
                half8v pv = *(const half8v*)(&s_post[p*PDIM + lane*8]);
                float sdot = 0.f;
                #pragma unroll
                for (int j = 0; j < 8; ++j) sdot += (float)pv[j] * (float)qv[j];
                sdot = wave_sum(sdot);
                if (lane == 0) s_scores[p] = (p0 + p < plen) ? sdot : -1e30f;
            }
            __syncthreads();
            if (wv == 0) {
                float m = (lane < 40) ? s_scores[lane] : -1e30f;
                m = wave_max(m);
                if (lane == 0) s_bc[0] = m;
            }
            __syncthreads();
            const float mx = s_bc[0];
            if (tid < 40) {
                float w = (p0 + tid < plen) ? __expf(s_scores[tid] - mx) : 0.f;
                s_w[tid] = w;
            }
            __syncthreads();
            if (wv == 0) {
                float sw = (lane < 40) ? s_w[lane] : 0.f;
                sw = wave_sum(sw);
                if (lane == 0) { pm[ab*4 + aq] = mx; pS[ab*4 + aq] = sw; }
            }
            // partial context: each thread owns 2 d's (half2 LDS reads)
            const int d0 = tid * 2;
            float ca = 0.f, cb = 0.f;
            for (int p = 0; p < 40; ++p) {
                float wp = s_w[p];
                half2v pv2 = *(const half2v*)&s_post[p*PDIM + d0];
                ca += wp * (float)pv2[0];
                cb += wp * (float)pv2[1];
            }
            pc[((size_t)ab*4 + aq)*PDIM + d0]     = ca;
            pc[((size_t)ab*4 + aq)*PDIM + d0 + 1] = cb;
            // quad sync: padded per-member flags, store + poll (no RMW)
            __syncthreads();
            if (tid == 0)
                __hip_atomic_store(&qarr[((ab<<2)|aq)*32], (unsigned)(t+1),
                                   __ATOMIC_RELEASE, __HIP_MEMORY_SCOPE_AGENT);
            if (tid < 4) {
                unsigned* sl = &qarr[((ab<<2)|tid)*32];
                while (__hip_atomic_load(sl, __ATOMIC_RELAXED, __HIP_MEMORY_SCOPE_AGENT) < (unsigned)(t+1))
                    __builtin_amdgcn_s_sleep(1);
                __hip_atomic_load(sl, __ATOMIC_ACQUIRE, __HIP_MEMORY_SCOPE_AGENT);
            }
            __syncthreads();
            // combine the 4 partials for our 128-d range -> fp16 ctx
            if (tid < 128) {
                const int d = aq*128 + tid;
                float m0 = pm[ab*4+0], m1 = pm[ab*4+1], m2 = pm[ab*4+2], m3 = pm[ab*4+3];
                float mm = fmaxf(fmaxf(m0, m1), fmaxf(m2, m3));
                float a0 = __expf(m0-mm), a1 = __expf(m1-mm), a2 = __expf(m2-mm), a3 = __expf(m3-mm);
                float den = a0*pS[ab*4+0] + a1*pS[ab*4+1] + a2*pS[ab*4+2] + a3*pS[ab*4+3];
                float val = a0*pc[((size_t)ab*4+0)*PDIM + d] + a1*pc[((size_t)ab*4+1)*PDIM + d]
                          + a2*pc[((size_t)ab*4+2)*PDIM + d] + a3*pc[((size_t)ab*4+3)*PDIM + d];
                ctx_h[(size_t)ab*PDIM + d] = (_Float16)(val / den);
            }
        }
        gbar(ctrlU, gen, tid, blk);

        // ======== stage C: ctx matmul + gates + h_new (64 blocks x 16 h-cols) ========
        if (blk < 64) {
            const int j0 = blk * 16;
            f32x4 aR = {0.f,0.f,0.f,0.f}, aZ = {0.f,0.f,0.f,0.f}, aN = {0.f,0.f,0.f,0.f};
            const _Float16* ctxA = ctx_h + (size_t)(wv*16)*PDIM;
            mfma_acc(aR, ctxA, PDIM, wih_h + (size_t)(       j0)*HDIM + 512, HDIM, PDIM/32, lane);
            mfma_acc(aZ, ctxA, PDIM, wih_h + (size_t)(1024 + j0)*HDIM + 512, HDIM, PDIM/32, lane);
            mfma_acc(aN, ctxA, PDIM, wih_h + (size_t)(2048 + j0)*HDIM + 512, HDIM, PDIM/32, lane);
            const int j  = j0 + (lane & 15);
            const int r0 = wv*16 + ((lane >> 4) << 2);
            #pragma unroll
            for (int r = 0; r < 4; ++r) {
                const int b = r0 + r;
                float gr = gacc[(size_t)b*G3 +        j] + aR[r];
                float gz = gacc[(size_t)b*G3 + 1024 + j] + aZ[r];
                float gn = gacc[(size_t)b*G3 + 2048 + j] + aN[r];
                float gh = ghn[(size_t)b*HDIM + j];
                float rg = 1.f / (1.f + __expf(-gr));
                float zg = 1.f / (1.f + __expf(-gz));
                float e2 = __expf(2.f * (gn + rg * gh));
                float ng = 1.f - 2.f / (e2 + 1.f);            // tanh
                float hv = (1.f - zg) * ng + zg * hp[r];
                if (lenb[r] <= t) hv = 0.f;
                hp[r] = hv;
                out[(size_t)t*BATCH*HDIM + (size_t)b*HDIM + j] = hv;
                h_h[(size_t)b*HDIM + j] = (_Float16)hv;
                if (t == S_LEN - 1)
                    out[(size_t)S_LEN*BATCH*HDIM + (size_t)b*HDIM + j] = hv;   // h_last
            }
        }
        if (t < S_LEN - 1) gbar(ctrlU, gen, tid, blk);
    }
}

extern "C" void kernel_launch(void* const* d_in, const int* in_sizes, int n_in,
                              void* d_out, int out_size, void* d_ws, size_t ws_size,
                              hipStream_t stream) {
    (void)in_sizes; (void)n_in; (void)out_size; (void)ws_size;
    const float* incoming    = (const float*)d_in[0];
    const float* post        = (const float*)d_in[1];
    const float* h_init      = (const float*)d_in[2];
    const float* w_ih        = (const float*)d_in[3];
    const float* w_hh        = (const float*)d_in[4];
    const float* b_ih        = (const float*)d_in[5];
    const float* b_hh        = (const float*)d_in[6];
    const float* wq          = (const float*)d_in[7];
    const float* bq          = (const float*)d_in[8];
    const int*   length      = (const int*)d_in[9];
    const int*   post_length = (const int*)d_in[10];
    float* out = (float*)d_out;

    init_ctrl<<<96, 256, 0, stream>>>((unsigned*)d_ws);
    gru_main<<<NBLK, NTHR, 0, stream>>>(incoming, post, h_init, w_ih, w_hh, b_ih, b_hh,
                                        wq, bq, length, post_length, out, (char*)d_ws);
}